// Round 4
// baseline (670.506 us; speedup 1.0000x reference)
//
#include <hip/hip_runtime.h>
#include <math.h>

#define B_ 2
#define L_ 2048
#define DMODEL 2048
#define DINNER 4096
#define DSTATE 16
#define DCONV 4
#define DTRANK 128
#define NCHUNK 32
#define CLEN 64           // L_/NCHUNK
#define MROWS 4096        // B_*L_

typedef unsigned short ushort_t;
typedef unsigned int uint_t;
typedef __attribute__((ext_vector_type(8))) short bf16x8;
typedef __attribute__((ext_vector_type(4))) float floatx4;

__device__ __forceinline__ float sigmoidf_(float x){ return 1.f/(1.f+__expf(-x)); }
__device__ __forceinline__ ushort_t f2bf(float f){
    uint_t u = __builtin_bit_cast(uint_t, f);
    return (ushort_t)((u + 0x7FFFu + ((u >> 16) & 1u)) >> 16);
}
__device__ __forceinline__ float bf2f(ushort_t h){
    return __builtin_bit_cast(float, (uint_t)h << 16);
}
__device__ __forceinline__ float fast_exp2(float x){
#if __has_builtin(__builtin_amdgcn_exp2f)
    return __builtin_amdgcn_exp2f(x);
#else
    return exp2f(x);
#endif
}
#define LOG2E 1.44269504088896f

#define GLD_LDS16(g, l) __builtin_amdgcn_global_load_lds( \
    (const __attribute__((address_space(1))) void*)(g),   \
    (__attribute__((address_space(3))) void*)(l), 16, 0, 0)

// ---------------------------------------------------------------------------
// 128x128 bf16 MFMA GEMM (m97 structure) — used for x_proj (split-K, N=256),
// dt_proj (K=128), out_proj (N=2048 -> 512 blocks fill the machine).
// ---------------------------------------------------------------------------
template<int OUTBF, int EPI, int SPLIT, int KSPLIT>
__global__ __launch_bounds__(256)
void gemm_mfma(const ushort_t* __restrict__ Aptr, int lda,
               const ushort_t* __restrict__ W, int ldw,
               void* __restrict__ Cptr, void* __restrict__ C2,
               int ldc, int Klen,
               const float* __restrict__ bias)
{
    __shared__ ushort_t lsA[128*64];
    __shared__ ushort_t lsW[128*64];
    const int tid  = threadIdx.x;
    const int row0 = blockIdx.x * 128;
    const int col0 = blockIdx.y * 128;
    const int koff = KSPLIT ? blockIdx.z * Klen : 0;
    const int lane = tid & 63;
    const int wv   = tid >> 6;
    const int wm   = (wv >> 1) * 64;
    const int wn   = (wv & 1) * 64;
    const int lr   = lane & 15;
    const int lq   = lane >> 4;

    floatx4 acc[4][4];
    #pragma unroll
    for(int i=0;i<4;i++)
        #pragma unroll
        for(int j=0;j<4;j++)
            #pragma unroll
            for(int r=0;r<4;r++) acc[i][j][r] = 0.f;

    for(int k0 = koff; k0 < koff + Klen; k0 += 64){
        #pragma unroll
        for(int it=0; it<4; it++){
            const int slot = it*256 + tid;
            const int row  = slot >> 3;
            const int p    = slot & 7;
            const int s    = p ^ (row & 7);
            const ushort_t* gw = W    + (size_t)(col0 + row)*ldw + k0 + s*8;
            const ushort_t* ga = Aptr + (size_t)(row0 + row)*lda + k0 + s*8;
            GLD_LDS16(gw, &lsW[slot*8]);
            GLD_LDS16(ga, &lsA[slot*8]);
        }
        __syncthreads();

        #pragma unroll
        for(int kk=0; kk<2; kk++){
            bf16x8 af[4], bw[4];
            #pragma unroll
            for(int i=0;i<4;i++){
                const int ra = wm + i*16 + lr;
                const int rb = wn + i*16 + lr;
                af[i] = *(const bf16x8*)&lsA[ra*64 + (((kk*4+lq) ^ (ra&7))*8)];
                bw[i] = *(const bf16x8*)&lsW[rb*64 + (((kk*4+lq) ^ (rb&7))*8)];
            }
            #pragma unroll
            for(int i=0;i<4;i++)
                #pragma unroll
                for(int j=0;j<4;j++)
                    acc[i][j] = __builtin_amdgcn_mfma_f32_16x16x32_bf16(af[i], bw[j], acc[i][j], 0, 0, 0);
        }
        __syncthreads();
    }

    void* dst = Cptr;
    int cbase = col0;
    if (SPLIT && col0 >= ldc){ dst = C2; cbase = col0 - ldc; }
    const size_t zoff = KSPLIT ? (size_t)blockIdx.z * MROWS * ldc : 0;

    #pragma unroll
    for(int i=0;i<4;i++){
        #pragma unroll
        for(int r=0;r<4;r++){
            const int row = row0 + wm + i*16 + lq*4 + r;
            #pragma unroll
            for(int j=0;j<4;j++){
                const int col = cbase + wn + j*16 + lr;
                float v = acc[i][j][r];
                if (EPI){
                    v += bias[col];
                    v = (v > 20.f) ? v : log1pf(expf(v));
                }
                if (OUTBF) ((ushort_t*)dst)[(size_t)row*ldc + col] = f2bf(v);
                else       ((float*)  dst)[zoff + (size_t)row*ldc + col] = v;
            }
        }
    }
}

// ---------------------------------------------------------------------------
// 256x256 bf16 GEMM v4: C[M,N]=A[M,K]*W[N,K]^T. 512 thr = 8 waves (2M x 4N),
// per-wave output 128x64, BK=64. LDS 128 KiB = [buf][A/W][khalf][256x32]
// -> only 1 block/CU (LDS-capped), 2 waves/SIMD.
// v4 schedule — intra-wave software pipeline (read-ahead both K-halves):
//   per K-tile t (c=t&1):
//     s_waitcnt vmcnt(0); s_barrier;       // tile t landed (issued @t-1)
//     STG tile t+1 -> buf c^1;             // 8 gload_lds
//     issue ALL 24 ds_read_b128 (kh0 set + kh1 set, 2 frag reg sets);
//     sched_barrier(0);                    // pin: no sinking reads below MFMA
//     MFMA(kh0) x32;   // compiler's counted lgkmcnt: starts after ~12 reads,
//                      // kh1's 12 reads (~770-1150 cyc CU-wide) drain under
//                      // MFMA(kh0)'s ~1240 cyc/SIMD
//     MFMA(kh1) x32;   // lgkmcnt(0) already satisfied
//   Modeled wall/tile ~3400 cyc vs v3's measured 5138 (fully serialized).
//   WAR: buf c^1 STG vs tile t-1 reads — every wave drained its own reads
//   (lgkm waits before its MFMAs) before arriving at the tile-t barrier.
// Swizzle (unchanged, 0 conflicts measured): chunk f of double-row dr holds
// (row 2dr+b, K-seg s), b*4+s = f^(dr&7); linear gload_lds dest, pre-swizzled
// per-lane source; ds_read slot f = ((lr&1)*4+lq)^(lr>>1).
// ---------------------------------------------------------------------------
template<int OUTBF, int SPLIT, int KSPLIT>
__global__ __launch_bounds__(512, 2)
void gemm_256(const ushort_t* __restrict__ Aptr, int lda,
              const ushort_t* __restrict__ W, int ldw,
              void* __restrict__ Cptr, void* __restrict__ C2,
              int ldc, int Klen)
{
    __shared__ ushort_t lds[2][2][2][8192];   // [buf][A/W][khalf][256x32]
    const int tid  = threadIdx.x;
    const int row0 = blockIdx.x * 256;
    const int col0 = blockIdx.y * 256;
    const int koff = KSPLIT ? blockIdx.z * Klen : 0;
    const int NT   = Klen >> 6;
    const int lane = tid & 63;
    const int wv   = tid >> 6;
    const int wr   = wv >> 2;          // 0..1 : M half (128 rows)
    const int wc   = wv & 3;           // 0..3 : N quarter (64 cols)
    const int lr   = lane & 15;
    const int lq   = lane >> 4;

    // staging: chunk g = it*512+tid in [0,1024): dr=g>>3, f=g&7, u=f^(dr&7)
    // -> source row 2*dr+(u>>2), source K-seg (u&3)*8; LDS dest linear g*8.
    int sdst0, sdst1;
    const ushort_t *aS0, *aS1, *wS0, *wS1;
    {
        const int g0 = tid,     dr0 = g0 >> 3, f0 = g0 & 7;
        const int g1 = 512+tid, dr1 = g1 >> 3, f1 = g1 & 7;
        const int u0 = f0 ^ (dr0 & 7), u1 = f1 ^ (dr1 & 7);
        const int r0s = dr0*2 + (u0 >> 2), c0s = (u0 & 3)*8;
        const int r1s = dr1*2 + (u1 >> 2), c1s = (u1 & 3)*8;
        sdst0 = g0*8; sdst1 = g1*8;
        aS0 = Aptr + (size_t)(row0 + r0s)*lda + c0s;
        aS1 = Aptr + (size_t)(row0 + r1s)*lda + c1s;
        wS0 = W    + (size_t)(col0 + r0s)*ldw + c0s;
        wS1 = W    + (size_t)(col0 + r1s)*ldw + c1s;
    }
    #define STG_A(kc, reg) { GLD_LDS16(aS0 + (kc), &(reg)[sdst0]); \
                             GLD_LDS16(aS1 + (kc), &(reg)[sdst1]); }
    #define STG_W(kc, reg) { GLD_LDS16(wS0 + (kc), &(reg)[sdst0]); \
                             GLD_LDS16(wS1 + (kc), &(reg)[sdst1]); }

    // ds_read base (ushort units): fragment i at base + i*512
    const int frd = ((lr & 1)*4 + lq) ^ (lr >> 1);
    const int aA  = (wr*64 + (lr >> 1))*64 + frd*8;
    const int aB  = (wc*32 + (lr >> 1))*64 + frd*8;

    floatx4 acc[8][4];
    #pragma unroll
    for(int i=0;i<8;i++)
        #pragma unroll
        for(int j=0;j<4;j++)
            #pragma unroll
            for(int r=0;r<4;r++) acc[i][j][r] = 0.f;

    // prologue: stage tile 0 into buf 0 (8 loads)
    STG_A(koff,    lds[0][0][0]);
    STG_A(koff+32, lds[0][0][1]);
    STG_W(koff,    lds[0][1][0]);
    STG_W(koff+32, lds[0][1][1]);

    for(int t=0; t<NT; ++t){
        const int c = t & 1;
        asm volatile("s_waitcnt vmcnt(0)\ns_barrier" ::: "memory");
        const int kn = koff + (t+1)*64;
        if (t+1 < NT){
            STG_A(kn,    lds[c^1][0][0]);
            STG_A(kn+32, lds[c^1][0][1]);
            STG_W(kn,    lds[c^1][1][0]);
            STG_W(kn+32, lds[c^1][1][1]);
        }
        const ushort_t* pA0 = lds[c][0][0];
        const ushort_t* pB0 = lds[c][1][0];
        const ushort_t* pA1 = lds[c][0][1];
        const ushort_t* pB1 = lds[c][1][1];
        bf16x8 a0[8], b0v[4], a1[8], b1v[4];
        #pragma unroll
        for(int j=0;j<4;j++) b0v[j] = *(const bf16x8*)&pB0[aB + j*512];
        #pragma unroll
        for(int i=0;i<8;i++) a0[i]  = *(const bf16x8*)&pA0[aA + i*512];
        #pragma unroll
        for(int j=0;j<4;j++) b1v[j] = *(const bf16x8*)&pB1[aB + j*512];
        #pragma unroll
        for(int i=0;i<8;i++) a1[i]  = *(const bf16x8*)&pA1[aA + i*512];
        __builtin_amdgcn_sched_barrier(0);   // pin all 24 reads before MFMAs
        __builtin_amdgcn_s_setprio(1);
        #pragma unroll
        for(int i=0;i<8;i++)
            #pragma unroll
            for(int j=0;j<4;j++)
                acc[i][j] = __builtin_amdgcn_mfma_f32_16x16x32_bf16(a0[i], b0v[j], acc[i][j],0,0,0);
        #pragma unroll
        for(int i=0;i<8;i++)
            #pragma unroll
            for(int j=0;j<4;j++)
                acc[i][j] = __builtin_amdgcn_mfma_f32_16x16x32_bf16(a1[i], b1v[j], acc[i][j],0,0,0);
        __builtin_amdgcn_s_setprio(0);
    }
    #undef STG_A
    #undef STG_W

    void* dst = Cptr;
    int cb = col0;
    if (SPLIT && col0 >= ldc){ dst = C2; cb = col0 - ldc; }
    const size_t zoff = KSPLIT ? (size_t)blockIdx.z * MROWS * ldc : 0;
    const int rbase = row0 + wr*128 + lq*4;
    const int cbase = cb + wc*64 + lr;
    #pragma unroll
    for(int i=0;i<8;i++){
        #pragma unroll
        for(int r=0;r<4;r++){
            const int row = rbase + i*16 + r;
            #pragma unroll
            for(int j=0;j<4;j++){
                const int col = cbase + j*16;
                const float v = acc[i][j][r];
                if (OUTBF) ((ushort_t*)dst)[(size_t)row*ldc + col] = f2bf(v);
                else       ((float*)dst)[zoff + (size_t)row*ldc + col] = v;
            }
        }
    }
}

// f32 -> bf16 cast, 4 elems/thread
__global__ __launch_bounds__(256)
void cvt_bf16(const float* __restrict__ in, ushort_t* __restrict__ out, int n4)
{
    const int i = blockIdx.x*256 + threadIdx.x;
    if (i < n4){
        float4 v = *(const float4*)(in + (size_t)i*4);
        union { ushort_t u[4]; uint2 q; } p;
        p.u[0]=f2bf(v.x); p.u[1]=f2bf(v.y); p.u[2]=f2bf(v.z); p.u[3]=f2bf(v.w);
        *(uint2*)(out + (size_t)i*4) = p.q;
    }
}

// w_xproj 160x4096 f32 -> 256x4096 bf16, rows 160..255 zero
__global__ __launch_bounds__(256)
void cvt_pad256(const float* __restrict__ in, ushort_t* __restrict__ out)
{
    const int i = blockIdx.x*256 + threadIdx.x;
    const int row = i >> 10;
    const int c4  = i & 1023;
    union { ushort_t u[4]; uint2 q; } p;
    if (row < 160){
        float4 v = *(const float4*)(in + (size_t)row*4096 + c4*4);
        p.u[0]=f2bf(v.x); p.u[1]=f2bf(v.y); p.u[2]=f2bf(v.z); p.u[3]=f2bf(v.w);
    } else { p.u[0]=0; p.u[1]=0; p.u[2]=0; p.u[3]=0; }
    *(uint2*)(out + (size_t)i*4) = p.q;
}

// reduce split-K partials P[8][4096][256] -> xdbl f32 (ld 160) + dtlo bf16 (ld 128)
__global__ __launch_bounds__(256)
void reduce_xproj(const float* __restrict__ P, float* __restrict__ xdbl,
                  ushort_t* __restrict__ dtlo)
{
    const int row = blockIdx.x;
    const int col = threadIdx.x;
    float s = 0.f;
    #pragma unroll
    for(int z=0; z<8; z++)
        s += P[(size_t)z*MROWS*256 + (size_t)row*256 + col];
    if (col < 160) xdbl[(size_t)row*160 + col] = s;
    if (col < DTRANK) dtlo[(size_t)row*DTRANK + col] = f2bf(s);
}

// depthwise causal conv (k=4) + bias + silu, bf16 in/out
__global__ __launch_bounds__(256)
void conv_silu_bf(const ushort_t* __restrict__ xb, const float* __restrict__ w,
                  const float* __restrict__ bias, ushort_t* __restrict__ xc)
{
    const int gid = blockIdx.x*256 + threadIdx.x;
    const int d = gid & (DINNER-1);
    const int t = gid >> 12;
    const int l = t & (L_-1);
    float s = bias[d];
    #pragma unroll
    for(int j=0;j<DCONV;j++){
        const int ll = l - (DCONV-1) + j;
        if (ll >= 0)
            s = fmaf(bf2f(xb[(size_t)(t-(DCONV-1)+j)*DINNER + d]), w[d*DCONV+j], s);
    }
    xc[(size_t)t*DINNER + d] = f2bf(s * sigmoidf_(s));
}

// ---- chunked scan, one thread per channel d, 16 states in registers ----
__global__ __launch_bounds__(256)
void scan_phase1(const ushort_t* __restrict__ dt_bf,
                 const ushort_t* __restrict__ xconv,
                 const float* __restrict__ xdbl,
                 const float* __restrict__ A_log,
                 float* __restrict__ sc_h, float* __restrict__ sc_S)
{
    const int tid = threadIdx.x;
    const int d = blockIdx.x*256 + tid;
    const int chunk = blockIdx.y;
    const int b = blockIdx.z;
    const int l0 = chunk*CLEN;

    __shared__ float Bs[CLEN][DSTATE];
    for(int i=tid; i<CLEN*DSTATE; i+=256){
        const int row = i >> 4, n = i & 15;
        Bs[row][n] = xdbl[(size_t)(b*L_ + l0 + row)*160 + DTRANK + n];
    }
    float negA[DSTATE];
    #pragma unroll
    for(int n=0;n<DSTATE;n++) negA[n] = -expf(A_log[d*DSTATE + n]) * LOG2E;
    __syncthreads();

    float h[DSTATE], S[DSTATE];
    #pragma unroll
    for(int n=0;n<DSTATE;n++){ h[n]=0.f; S[n]=0.f; }

    size_t idx = (size_t)(b*L_ + l0)*DINNER + d;
    float dt_c = bf2f(dt_bf[idx]);
    float xv_c = bf2f(xconv[idx]);
    for(int l=0;l<CLEN;l++){
        float dt_n = 0.f, xv_n = 0.f;
        if (l+1 < CLEN){
            dt_n = bf2f(dt_bf[idx + DINNER]);
            xv_n = bf2f(xconv[idx + DINNER]);
        }
        const float dx = dt_c * xv_c;
        #pragma unroll
        for(int n=0;n<DSTATE;n++){
            const float t = dt_c * negA[n];
            S[n] += t;
            h[n] = fmaf(h[n], fast_exp2(t), dx*Bs[l][n]);
        }
        dt_c = dt_n; xv_c = xv_n;
        idx += DINNER;
    }
    const size_t o = (size_t)(b*NCHUNK + chunk)*DSTATE*DINNER + d;
    #pragma unroll
    for(int n=0;n<DSTATE;n++){
        sc_h[o + (size_t)n*DINNER] = h[n];
        sc_S[o + (size_t)n*DINNER] = S[n];
    }
}

__global__ __launch_bounds__(256)
void scan_phase2(float* __restrict__ sc_h, const float* __restrict__ sc_S)
{
    const int gid = blockIdx.x*256 + threadIdx.x;
    const int b = gid / (DSTATE*DINNER);
    const int rem = gid - b*DSTATE*DINNER;
    const size_t base = (size_t)b*NCHUNK*DSTATE*DINNER + rem;
    float H = 0.f;
    #pragma unroll
    for(int c=0;c<NCHUNK;c++){
        const size_t idx = base + (size_t)c*DSTATE*DINNER;
        const float he = sc_h[idx];
        const float S  = sc_S[idx];
        sc_h[idx] = H;
        H = fmaf(fast_exp2(S), H, he);
    }
}

__global__ __launch_bounds__(256)
void scan_phase3(const ushort_t* __restrict__ dt_bf,
                 const ushort_t* __restrict__ xconv,
                 const float* __restrict__ xdbl,
                 const ushort_t* __restrict__ z_bf,
                 const float* __restrict__ A_log,
                 const float* __restrict__ Dvec,
                 const float* __restrict__ sc_h,
                 ushort_t* __restrict__ y_bf)
{
    const int tid = threadIdx.x;
    const int d = blockIdx.x*256 + tid;
    const int chunk = blockIdx.y;
    const int b = blockIdx.z;
    const int l0 = chunk*CLEN;

    __shared__ float BCs[CLEN][2*DSTATE];
    for(int i=tid; i<CLEN*2*DSTATE; i+=256){
        const int row = i >> 5, c = i & 31;
        BCs[row][c] = xdbl[(size_t)(b*L_ + l0 + row)*160 + DTRANK + c];
    }
    float negA[DSTATE];
    #pragma unroll
    for(int n=0;n<DSTATE;n++) negA[n] = -expf(A_log[d*DSTATE + n]) * LOG2E;
    const float Dv = Dvec[d];
    float h[DSTATE];
    const size_t o = (size_t)(b*NCHUNK + chunk)*DSTATE*DINNER + d;
    #pragma unroll
    for(int n=0;n<DSTATE;n++) h[n] = sc_h[o + (size_t)n*DINNER];
    __syncthreads();

    size_t idx = (size_t)(b*L_ + l0)*DINNER + d;
    float dt_c = bf2f(dt_bf[idx]);
    float xv_c = bf2f(xconv[idx]);
    float zv_c = bf2f(z_bf[idx]);
    for(int l=0;l<CLEN;l++){
        float dt_n = 0.f, xv_n = 0.f, zv_n = 0.f;
        if (l+1 < CLEN){
            dt_n = bf2f(dt_bf[idx + DINNER]);
            xv_n = bf2f(xconv[idx + DINNER]);
            zv_n = bf2f(z_bf[idx + DINNER]);
        }
        const float dx = dt_c * xv_c;
        float y = 0.f;
        #pragma unroll
        for(int n=0;n<DSTATE;n++){
            const float t = dt_c * negA[n];
            h[n] = fmaf(h[n], fast_exp2(t), dx*BCs[l][n]);
            y = fmaf(h[n], BCs[l][DSTATE+n], y);
        }
        const float g = zv_c * sigmoidf_(zv_c);
        y_bf[idx] = f2bf(fmaf(xv_c, Dv, y) * g);
        dt_c = dt_n; xv_c = xv_n; zv_c = zv_n;
        idx += DINNER;
    }
}

extern "C" void kernel_launch(void* const* d_in, const int* in_sizes, int n_in,
                              void* d_out, int out_size, void* d_ws, size_t ws_size,
                              hipStream_t stream) {
    const float* hs      = (const float*)d_in[0];
    const float* w_in    = (const float*)d_in[1];
    const float* w_conv  = (const float*)d_in[2];
    const float* b_conv  = (const float*)d_in[3];
    const float* w_xproj = (const float*)d_in[4];
    const float* w_dt    = (const float*)d_in[5];
    const float* b_dt    = (const float*)d_in[6];
    const float* w_out   = (const float*)d_in[7];
    const float* A_log   = (const float*)d_in[8];
    const float* Dvec    = (const float*)d_in[9];
    float* out = (float*)d_out;

    // workspace layout (peak 176 MiB):
    // [0,32M)    x_bf -> after conv: xdbl@0, wx_bf@4M, dtlo@6M, wdt@7M, sc_h@8M(16M)
    // [32M,64M)  z_bf               (live to phase3)
    // [64M,96M)  xconv              (live to phase3)
    // [96M,128M) wi_bf -> after in_proj: dt_bf
    // [128M,144M) hs_bf -> after in_proj: sc_S -> after phase2: wo_bf
    // [144M,176M) y_bf  (also x_proj split-K partials, dead before phase3)
    char* base = (char*)d_ws;
    ushort_t* x_bf   = (ushort_t*)(base);
    float*    xdbl   = (float*)   (base);
    ushort_t* wx_bf  = (ushort_t*)(base + (4u<<20));
    ushort_t* dtlo_bf= (ushort_t*)(base + (6u<<20));
    ushort_t* wdt_bf = (ushort_t*)(base + (7u<<20));
    float*    sc_h   = (float*)   (base + (8u<<20));
    ushort_t* z_bf   = (ushort_t*)(base + (32u<<20));
    ushort_t* xconv  = (ushort_t*)(base + (64u<<20));
    ushort_t* wi_bf  = (ushort_t*)(base + (96u<<20));
    ushort_t* dt_bf  = (ushort_t*)(base + (96u<<20));
    ushort_t* hs_bf  = (ushort_t*)(base + (128u<<20));
    float*    sc_S   = (float*)   (base + (128u<<20));
    ushort_t* wo_bf  = (ushort_t*)(base + (128u<<20));
    float*    xp_par = (float*)   (base + (144u<<20));  // 8*4096*256*4 = 32 MiB
    ushort_t* y_bf   = (ushort_t*)(base + (144u<<20));

    dim3 blk(256);
    dim3 blk5(512);

    // convert activations + in_proj weights to bf16
    cvt_bf16<<<dim3(MROWS*DMODEL/4/256), blk, 0, stream>>>(hs, hs_bf, MROWS*DMODEL/4);
    cvt_bf16<<<dim3(2*DINNER*DMODEL/4/256), blk, 0, stream>>>(w_in, wi_bf, 2*DINNER*DMODEL/4);

    // fused in_proj (256^2 v4 pipelined schedule): N=8192, split x / z halves
    gemm_256<1,1,0><<<dim3(MROWS/256, 2*DINNER/256), blk5, 0, stream>>>(
        hs_bf, DMODEL, wi_bf, DMODEL, x_bf, z_bf, DINNER, DMODEL);

    // conv + silu -> xconv bf16 (x_bf region becomes free after this)
    conv_silu_bf<<<dim3((size_t)MROWS*DINNER/256), blk, 0, stream>>>(x_bf, w_conv, b_conv, xconv);

    // x_proj: split-K x 8 into f32 partials, then reduce (+fused dtlo cvt)
    cvt_pad256<<<dim3(256*4096/4/256), blk, 0, stream>>>(w_xproj, wx_bf);
    gemm_mfma<0,0,0,1><<<dim3(MROWS/128, 2, 8), blk, 0, stream>>>(
        xconv, DINNER, wx_bf, DINNER, xp_par, nullptr, 256, DINNER/8, nullptr);
    reduce_xproj<<<dim3(MROWS), blk, 0, stream>>>(xp_par, xdbl, dtlo_bf);

    // dt_proj + bias + softplus -> dt_bf (overwrites dead wi_bf region)
    cvt_bf16<<<dim3(DINNER*DTRANK/4/256), blk, 0, stream>>>(w_dt, wdt_bf, DINNER*DTRANK/4);
    gemm_mfma<1,1,0,0><<<dim3(MROWS/128, DINNER/128), blk, 0, stream>>>(
        dtlo_bf, DTRANK, wdt_bf, DTRANK, dt_bf, nullptr, DINNER, DTRANK, b_dt);

    // chunked selective scan (thread-per-channel, coalesced)
    dim3 sgrid(DINNER/256, NCHUNK, B_);
    scan_phase1<<<sgrid, blk, 0, stream>>>(dt_bf, xconv, xdbl, A_log, sc_h, sc_S);
    scan_phase2<<<dim3(B_*DSTATE*DINNER/256), blk, 0, stream>>>(sc_h, sc_S);

    // w_out conversion (sc_S dead after phase2; reuse its region)
    cvt_bf16<<<dim3(DMODEL*DINNER/4/256), blk, 0, stream>>>(w_out, wo_bf, DMODEL*DINNER/4);

    scan_phase3<<<sgrid, blk, 0, stream>>>(dt_bf, xconv, xdbl, z_bf, A_log, Dvec, sc_h, y_bf);

    // out_proj (128^2 kernel, 512 blocks -> full machine, direct f32 out)
    gemm_mfma<0,0,0,0><<<dim3(MROWS/128, DMODEL/128), blk, 0, stream>>>(
        y_bf, DINNER, wo_bf, DINNER, out, nullptr, DMODEL, DINNER, nullptr);
}